// Round 2
// baseline (1932.454 us; speedup 1.0000x reference)
//
#include <hip/hip_runtime.h>
#include <math.h>

#define HH 19
#define NB 1024
#define TT 2048

// readlane: VGPR -> wave-uniform (SGPR); ignores exec mask
__device__ __forceinline__ float rl(float v, int l) {
  return __uint_as_float(__builtin_amdgcn_readlane(__float_as_uint(v), l));
}
// fast v_rcp_f32 (~1 ulp) instead of the full div sequence
__device__ __forceinline__ float frcp(float v) {
  return __builtin_amdgcn_rcpf(v);
}

// One batch element per wave. Lane i (i<19) owns h_i and computes gates
// r_i, z_i, n_i entirely locally: 6 dot products against wave-uniform
// operands (x row + h broadcast in SGPRs). NO cross-lane ops except the
// 19 readlanes that refresh the uniform h copy. Lanes 19..63 duplicate
// row 18 (results unused).
__global__ __launch_bounds__(64, 1) void gru_lane19_kernel(
    const float* __restrict__ x, const float* __restrict__ Wih,
    const float* __restrict__ Whh, const float* __restrict__ bih,
    const float* __restrict__ bhh, const float* __restrict__ Wout,
    const float* __restrict__ bout, float* __restrict__ out)
{
  const int b = blockIdx.x;
  const int lane = threadIdx.x;
  const int i = lane < HH ? lane : HH - 1;

  // 6 weight rows + Wout resident in VGPRs (constant indices only -> regs)
  float wir[HH], wiz[HH], win[HH], whr[HH], whz[HH], whn[HH], wo[HH];
#pragma unroll
  for (int k = 0; k < HH; ++k) {
    wir[k] = Wih[i * HH + k];
    wiz[k] = Wih[(HH + i) * HH + k];
    win[k] = Wih[(2 * HH + i) * HH + k];
    whr[k] = Whh[i * HH + k];
    whz[k] = Whh[(HH + i) * HH + k];
    whn[k] = Whh[(2 * HH + i) * HH + k];
    wo[k]  = Wout[k];
  }
  const float br  = bih[i] + bhh[i];            // r bias (combined)
  const float bz  = bih[HH + i] + bhh[HH + i];  // z bias (combined)
  const float bnx = bih[2 * HH + i];            // n: x-side bias
  const float bnh = bhh[2 * HH + i];            // n: h-side bias (inside r*(...))
  const float bo  = bout[0];

  float h = 0.0f;       // lane i holds h_i
  float sh[HH];         // wave-uniform h copy (SGPRs)
#pragma unroll
  for (int k = 0; k < HH; ++k) sh[k] = 0.0f;

  const float* __restrict__ xrow0 = x + (size_t)b * HH;

  // distance-3..4 step prefetch: 4 uniform row buffers, unroll-4 main loop
  float xA[HH], xB[HH], xC[HH], xD[HH];

#define LOADROW(dst, trow) do {                                   \
    const float* __restrict__ _p = xrow0 + (size_t)(trow) * (NB * HH); \
    _Pragma("unroll")                                             \
    for (int k = 0; k < HH; ++k) (dst)[k] = _p[k];                \
  } while (0)

  LOADROW(xA, 0); LOADROW(xB, 1); LOADROW(xC, 2); LOADROW(xD, 3);

#define STEP(xv, tcur) do {                                       \
    float axr = br, axz = bz, axn = bnx;                          \
    float ahr = 0.0f, ahz = 0.0f, ahn = bnh;                      \
    _Pragma("unroll")                                             \
    for (int k = 0; k < HH; ++k) {                                \
      axr = fmaf((xv)[k], wir[k], axr);                           \
      ahr = fmaf(sh[k],  whr[k], ahr);                            \
      axz = fmaf((xv)[k], wiz[k], axz);                           \
      ahz = fmaf(sh[k],  whz[k], ahz);                            \
      axn = fmaf((xv)[k], win[k], axn);                           \
      ahn = fmaf(sh[k],  whn[k], ahn);                            \
    }                                                             \
    const float prer = axr + ahr;                                 \
    const float prez = axz + ahz;                                 \
    const float rr = frcp(1.0f + __expf(-prer));                  \
    const float zz = frcp(1.0f + __expf(-prez));                  \
    const float npre = fmaf(rr, ahn, axn);                        \
    const float ee = __expf(2.0f * npre);                         \
    const float nn = 1.0f - 2.0f * frcp(ee + 1.0f);               \
    h = nn + zz * (h - nn);                                       \
    _Pragma("unroll")                                             \
    for (int k = 0; k < HH; ++k) sh[k] = rl(h, k);                \
    float oo = bo;                                                \
    _Pragma("unroll")                                             \
    for (int k = 0; k < HH; ++k) oo = fmaf(sh[k], wo[k], oo);     \
    if (lane == 0) out[(size_t)(tcur) * NB + b] = oo;             \
  } while (0)

  for (int t = 0; t < TT; t += 4) {
    STEP(xA, t);
    { const int tn = (t + 4 < TT) ? t + 4 : TT - 1; LOADROW(xA, tn); }
    STEP(xB, t + 1);
    { const int tn = (t + 5 < TT) ? t + 5 : TT - 1; LOADROW(xB, tn); }
    STEP(xC, t + 2);
    { const int tn = (t + 6 < TT) ? t + 6 : TT - 1; LOADROW(xC, tn); }
    STEP(xD, t + 3);
    { const int tn = (t + 7 < TT) ? t + 7 : TT - 1; LOADROW(xD, tn); }
  }

#undef LOADROW
#undef STEP
}

extern "C" void kernel_launch(void* const* d_in, const int* in_sizes, int n_in,
                              void* d_out, int out_size, void* d_ws, size_t ws_size,
                              hipStream_t stream) {
  const float* x    = (const float*)d_in[0];
  const float* Wih  = (const float*)d_in[1];
  const float* Whh  = (const float*)d_in[2];
  const float* bih  = (const float*)d_in[3];
  const float* bhh  = (const float*)d_in[4];
  const float* Wout = (const float*)d_in[5];
  const float* bout = (const float*)d_in[6];
  float* out = (float*)d_out;

  gru_lane19_kernel<<<dim3(NB), dim3(64), 0, stream>>>(
      x, Wih, Whh, bih, bhh, Wout, bout, out);
}

// Round 4
// 691.768 us; speedup vs baseline: 2.7935x; 2.7935x over previous
//
#include <hip/hip_runtime.h>
#include <math.h>

#define HH 19
#define NB 1024
#define TT 2048

typedef float v2f __attribute__((ext_vector_type(2)));

// readlane: VGPR -> wave-uniform SGPR; ignores exec mask
__device__ __forceinline__ float rl(float v, int l) {
  return __uint_as_float(__builtin_amdgcn_readlane(__float_as_uint(v), l));
}
// fast v_rcp_f32
__device__ __forceinline__ float frcp(float v) {
  return __builtin_amdgcn_rcpf(v);
}
// packed fma -> v_pk_fma_f32
__device__ __forceinline__ v2f vfma(v2f a, v2f b, v2f c) {
#if __has_builtin(__builtin_elementwise_fma)
  return __builtin_elementwise_fma(a, b, c);
#else
  v2f r; r.x = fmaf(a.x, b.x, c.x); r.y = fmaf(a.y, b.y, c.y); return r;
#endif
}

// One batch element per wave; lane i (<19) computes gates r_i,z_i,n_i locally
// (6 dots vs wave-uniform x row + h broadcast). No LDS, no shuffles; h is
// re-broadcast each step via 19 v_readlane. Weights prescaled by log2(e)
// (2*log2(e) for n) so activations need only v_exp_f32 (exp2).
// batch 1024 == chip SIMD count -> exactly 1 wave/SIMD; waves_per_eu(1,1)
// hands the allocator the full 512-VGPR file (round-2 spilled at a 96 cap).
__global__ void __launch_bounds__(64)
__attribute__((amdgpu_waves_per_eu(1, 1)))
gru_lane19_v3(const float* __restrict__ x, const float* __restrict__ Wih,
              const float* __restrict__ Whh, const float* __restrict__ bih,
              const float* __restrict__ bhh, const float* __restrict__ Wout,
              const float* __restrict__ bout, float* __restrict__ out)
{
  const int b = blockIdx.x;
  const int lane = threadIdx.x;
  const int i = lane < HH ? lane : HH - 1;

  const float L2E = 1.4426950408889634f;   // log2(e)
  const float L2E2 = 2.0f * L2E;

  // per-lane weight rows in VGPRs, packed as 10 x v2f (element 19 = 0 pad)
  v2f wir2[10], wiz2[10], win2[10], whr2[10], whz2[10], whn2[10], wo2[10];
#pragma unroll
  for (int j = 0; j < 10; ++j) {
    const int k0 = 2 * j, k1 = 2 * j + 1;
    const int r0 = i * HH, z0 = (HH + i) * HH, n0 = (2 * HH + i) * HH;
    wir2[j].x = Wih[r0 + k0] * L2E;
    wir2[j].y = (k1 < HH) ? Wih[r0 + k1] * L2E : 0.0f;
    wiz2[j].x = Wih[z0 + k0] * L2E;
    wiz2[j].y = (k1 < HH) ? Wih[z0 + k1] * L2E : 0.0f;
    win2[j].x = Wih[n0 + k0] * L2E2;
    win2[j].y = (k1 < HH) ? Wih[n0 + k1] * L2E2 : 0.0f;
    whr2[j].x = Whh[r0 + k0] * L2E;
    whr2[j].y = (k1 < HH) ? Whh[r0 + k1] * L2E : 0.0f;
    whz2[j].x = Whh[z0 + k0] * L2E;
    whz2[j].y = (k1 < HH) ? Whh[z0 + k1] * L2E : 0.0f;
    whn2[j].x = Whh[n0 + k0] * L2E2;
    whn2[j].y = (k1 < HH) ? Whh[n0 + k1] * L2E2 : 0.0f;
    wo2[j].x  = Wout[k0];
    wo2[j].y  = (k1 < HH) ? Wout[k1] : 0.0f;
  }
  const float br  = (bih[i] + bhh[i]) * L2E;
  const float bz  = (bih[HH + i] + bhh[HH + i]) * L2E;
  const float bnx = bih[2 * HH + i] * L2E2;
  const float bnh = bhh[2 * HH + i] * L2E2;
  const float bo  = bout[0];

  float h = 0.0f;     // lane i holds h_i
  v2f sh2[10];        // wave-uniform h copy (refreshed via readlane)
#pragma unroll
  for (int j = 0; j < 10; ++j) { sh2[j].x = 0.0f; sh2[j].y = 0.0f; }

  // laundered zero: forces x-row loads to VGPR global_loads (round 2: the
  // compiler scalarized these into the SGPR file and blew the scalar budget)
  int vz;
  asm("v_mov_b32 %0, 0" : "=v"(vz));

  // 4 prefetch row buffers in VGPRs; [9].y is permanent 0 pad
  v2f xA[10], xB[10], xC[10], xD[10];
  xA[9].y = 0.0f; xB[9].y = 0.0f; xC[9].y = 0.0f; xD[9].y = 0.0f;

#define LOADROW(dst, trow) do {                                         \
    const float* _p = x + ((size_t)(trow) * NB + b) * HH + vz;          \
    _Pragma("unroll")                                                   \
    for (int _j = 0; _j < 9; ++_j) {                                    \
      dst[_j].x = _p[2 * _j];                                           \
      dst[_j].y = _p[2 * _j + 1];                                       \
    }                                                                   \
    dst[9].x = _p[18];                                                  \
  } while (0)

  LOADROW(xA, 0); LOADROW(xB, 1); LOADROW(xC, 2); LOADROW(xD, 3);

#define STEP(xv2, tcur) do {                                            \
    v2f axr = {br, 0.0f}, axz = {bz, 0.0f}, axn = {bnx, 0.0f};          \
    v2f ahr = {0.0f, 0.0f}, ahz = {0.0f, 0.0f}, ahn = {bnh, 0.0f};      \
    _Pragma("unroll")                                                   \
    for (int _j = 0; _j < 10; ++_j) {                                   \
      axr = vfma(xv2[_j], wir2[_j], axr);                               \
      ahr = vfma(sh2[_j], whr2[_j], ahr);                               \
      axz = vfma(xv2[_j], wiz2[_j], axz);                               \
      ahz = vfma(sh2[_j], whz2[_j], ahz);                               \
      axn = vfma(xv2[_j], win2[_j], axn);                               \
      ahn = vfma(sh2[_j], whn2[_j], ahn);                               \
    }                                                                   \
    const v2f pr2 = axr + ahr;                                          \
    const v2f pz2 = axz + ahz;                                          \
    const float prer = pr2.x + pr2.y;                                   \
    const float prez = pz2.x + pz2.y;                                   \
    const float axnh = axn.x + axn.y;                                   \
    const float ahnh = ahn.x + ahn.y;                                   \
    const float rr = frcp(1.0f + exp2f(-prer));                         \
    const float zz = frcp(1.0f + exp2f(-prez));                         \
    const float npre = fmaf(rr, ahnh, axnh);                            \
    const float nn = fmaf(-2.0f, frcp(exp2f(npre) + 1.0f), 1.0f);       \
    h = fmaf(zz, h - nn, nn);                                           \
    _Pragma("unroll")                                                   \
    for (int _j = 0; _j < 9; ++_j) {                                    \
      sh2[_j].x = rl(h, 2 * _j);                                        \
      sh2[_j].y = rl(h, 2 * _j + 1);                                    \
    }                                                                   \
    sh2[9].x = rl(h, 18); sh2[9].y = 0.0f;                              \
    v2f oa = {bo, 0.0f};                                                \
    _Pragma("unroll")                                                   \
    for (int _j = 0; _j < 10; ++_j) oa = vfma(sh2[_j], wo2[_j], oa);    \
    if (lane == 0) out[(size_t)(tcur) * NB + b] = oa.x + oa.y;          \
  } while (0)

  for (int t = 0; t < TT; t += 4) {
    STEP(xA, t);
    { const int tn = (t + 4 < TT) ? t + 4 : TT - 1; LOADROW(xA, tn); }
    STEP(xB, t + 1);
    { const int tn = (t + 5 < TT) ? t + 5 : TT - 1; LOADROW(xB, tn); }
    STEP(xC, t + 2);
    { const int tn = (t + 6 < TT) ? t + 6 : TT - 1; LOADROW(xC, tn); }
    STEP(xD, t + 3);
    { const int tn = (t + 7 < TT) ? t + 7 : TT - 1; LOADROW(xD, tn); }
  }

#undef LOADROW
#undef STEP
}

extern "C" void kernel_launch(void* const* d_in, const int* in_sizes, int n_in,
                              void* d_out, int out_size, void* d_ws, size_t ws_size,
                              hipStream_t stream) {
  const float* x    = (const float*)d_in[0];
  const float* Wih  = (const float*)d_in[1];
  const float* Whh  = (const float*)d_in[2];
  const float* bih  = (const float*)d_in[3];
  const float* bhh  = (const float*)d_in[4];
  const float* Wout = (const float*)d_in[5];
  const float* bout = (const float*)d_in[6];
  float* out = (float*)d_out;

  gru_lane19_v3<<<dim3(NB), dim3(64), 0, stream>>>(
      x, Wih, Whh, bih, bhh, Wout, bout, out);
}

// Round 6
// 623.999 us; speedup vs baseline: 3.0969x; 1.1086x over previous
//
#include <hip/hip_runtime.h>
#include <math.h>

#define HH 19
#define NB 1024
#define TT 2048

typedef float v2f __attribute__((ext_vector_type(2)));
typedef unsigned u2 __attribute__((ext_vector_type(2)));

// readlane: VGPR -> wave-uniform SGPR; ignores exec mask
__device__ __forceinline__ float rl(float v, int l) {
  return __uint_as_float(__builtin_amdgcn_readlane(__float_as_uint(v), l));
}
__device__ __forceinline__ float frcp(float v) {
  return __builtin_amdgcn_rcpf(v);
}
// raw v_exp_f32 (exp2) — plain exp2f without fast-math emits a fixup sequence
__device__ __forceinline__ float fexp2(float v) {
#if __has_builtin(__builtin_amdgcn_exp2f)
  return __builtin_amdgcn_exp2f(v);
#else
  return exp2f(v);
#endif
}
__device__ __forceinline__ v2f vfma(v2f a, v2f b, v2f c) {
#if __has_builtin(__builtin_elementwise_fma)
  return __builtin_elementwise_fma(a, b, c);
#else
  v2f r; r.x = fmaf(a.x, b.x, c.x); r.y = fmaf(a.y, b.y, c.y); return r;
#endif
}

// halves-broadcast via permlane32_swap builtin (compiler-known semantics).
// swap(x,x) yields {lo-half bcast, hi-half bcast} in SOME order; a one-time
// probe decides which is which. Fallback: ds_bpermute with identical effect.
#if __has_builtin(__builtin_amdgcn_permlane32_swap)
#define HAVE_PLS 1
__device__ __forceinline__ u2 pls(float x) {
  unsigned u = __float_as_uint(x);
  return __builtin_amdgcn_permlane32_swap(u, u, false, false);
}
#else
#define HAVE_PLS 0
#endif

// 57-lane spread, one gate-row per lane:
//   lanes 0-18  : r-rows 0-18  (also h_i owner)
//   lanes 19-31 : z-rows 19-31 (z_i, i=0..12)
//   lanes 32-50 : n-rows 38-56 (n_i, i=0..18)  <- lane 32+i pairs with lane i
//   lanes 51-56 : z-rows 32-37 (z_i, i=13..18)
// r_i -> n-lane (lo-bcast) and n_i -> h-lane (hi-bcast) via permlane32_swap;
// z_i -> h-lane via one ds_bpermute (off the critical path).
__global__ void __launch_bounds__(64)
__attribute__((amdgpu_waves_per_eu(1, 1)))
gru57_v2(const float* __restrict__ x, const float* __restrict__ Wih,
         const float* __restrict__ Whh, const float* __restrict__ bih,
         const float* __restrict__ bhh, const float* __restrict__ Wout,
         const float* __restrict__ bout, float* __restrict__ out)
{
  const int b = blockIdx.x;
  const int lane = threadIdx.x;

  const float L2E = 1.4426950408889634f;   // log2(e)

  int row;
  if (lane < 32)      row = lane;          // r-rows 0-18, z-rows 19-31
  else if (lane < 51) row = lane + 6;      // n-rows 38-56
  else if (lane < 57) row = lane - 19;     // z-rows 32-37
  else                row = 37;            // idle lanes: harmless z-row
  const bool isn = (row >= 2 * HH);
  const float scale = isn ? (2.0f * L2E) : L2E;

  // per-lane weight row (x-side, h-side) + uniform Wout
  v2f wx2[10], wh2[10], wo2[10];
#pragma unroll
  for (int j = 0; j < 10; ++j) {
    const int k0 = 2 * j, k1 = 2 * j + 1;
    wx2[j].x = Wih[row * HH + k0] * scale;
    wx2[j].y = (k1 < HH) ? Wih[row * HH + k1] * scale : 0.0f;
    wh2[j].x = Whh[row * HH + k0] * scale;
    wh2[j].y = (k1 < HH) ? Whh[row * HH + k1] * scale : 0.0f;
    wo2[j].x = Wout[k0];
    wo2[j].y = (k1 < HH) ? Wout[k1] : 0.0f;
  }
  const float bxv = bih[row] * scale, bhv = bhh[row] * scale;
  const float ax0 = isn ? bxv : (bxv + bhv);  // n: h-bias stays inside r*(...)
  const float ah0 = isn ? bhv : 0.0f;
  const float bo  = bout[0];

  // z-gather source lane (h-owner lane i reads z_i), byte address
  const int il = lane < HH ? lane : HH - 1;
  const int zaddr = ((il < 13) ? (19 + il) : (38 + il)) * 4;

#if HAVE_PLS
  // one-time probe: which result of swap(x,x) is the LO-half broadcast?
  bool loIsX;
  {
    unsigned l = (unsigned)lane;
    u2 pr = __builtin_amdgcn_permlane32_swap(l, l, false, false);
    loIsX = ((unsigned)__builtin_amdgcn_readlane((int)pr.x, 32) < 32u);
  }
#else
  const int loaddr = (lane & 31) * 4;          // lo-bcast source lane
  const int hiaddr = ((lane & 31) | 32) * 4;   // hi-bcast source lane
#endif

  float h = 0.0f;      // lane i (<19) owns h_i
  v2f sh2[10];         // wave-uniform h copy (via readlane)
#pragma unroll
  for (int j = 0; j < 10; ++j) { sh2[j].x = 0.0f; sh2[j].y = 0.0f; }

  // laundered zero: keep x-row loads in the vector pipe (SGPR file is tight)
  int vz;
  asm("v_mov_b32 %0, 0" : "=v"(vz));

  v2f xA[10], xB[10], xC[10], xD[10];
  xA[9].y = 0.0f; xB[9].y = 0.0f; xC[9].y = 0.0f; xD[9].y = 0.0f;

#define LOADROW(dst, trow) do {                                         \
    const float* _p = x + ((size_t)(trow) * NB + b) * HH + vz;          \
    _Pragma("unroll")                                                   \
    for (int _j = 0; _j < 9; ++_j) {                                    \
      dst[_j].x = _p[2 * _j];                                           \
      dst[_j].y = _p[2 * _j + 1];                                       \
    }                                                                   \
    dst[9].x = _p[18];                                                  \
  } while (0)

  LOADROW(xA, 0); LOADROW(xB, 1); LOADROW(xC, 2); LOADROW(xD, 3);

#if HAVE_PLS
#define LOBCAST(val, dst) do { u2 _s = pls(val);                        \
    dst = __uint_as_float(loIsX ? _s.x : _s.y); } while (0)
#define HIBCAST(val, dst) do { u2 _s = pls(val);                        \
    dst = __uint_as_float(loIsX ? _s.y : _s.x); } while (0)
#else
#define LOBCAST(val, dst) dst = __uint_as_float((unsigned)               \
    __builtin_amdgcn_ds_bpermute(loaddr, (int)__float_as_uint(val)))
#define HIBCAST(val, dst) dst = __uint_as_float((unsigned)               \
    __builtin_amdgcn_ds_bpermute(hiaddr, (int)__float_as_uint(val)))
#endif

#define STEP(xv, tcur) do {                                             \
    v2f axA = {ax0, 0.0f}, axB = {0.0f, 0.0f};                          \
    v2f ahA = {ah0, 0.0f}, ahB = {0.0f, 0.0f};                          \
    _Pragma("unroll")                                                   \
    for (int _j = 0; _j < 5; ++_j) {                                    \
      axA = vfma(xv[_j], wx2[_j], axA);                                 \
      ahA = vfma(sh2[_j], wh2[_j], ahA);                                \
    }                                                                   \
    _Pragma("unroll")                                                   \
    for (int _j = 5; _j < 10; ++_j) {                                   \
      axB = vfma(xv[_j], wx2[_j], axB);                                 \
      ahB = vfma(sh2[_j], wh2[_j], ahB);                                \
    }                                                                   \
    const v2f axv = axA + axB;                                          \
    const v2f ahv = ahA + ahB;                                          \
    const float prex = axv.x + axv.y;                                   \
    const float preh = ahv.x + ahv.y;                                   \
    const float pre  = prex + preh;                                     \
    const float sig  = frcp(1.0f + fexp2(-pre));                        \
    /* z_i -> h-lane (latency hides under the n path) */                \
    const int zzi = __builtin_amdgcn_ds_bpermute(                       \
        zaddr, (int)__float_as_uint(sig));                              \
    /* r_i -> n-lane: lo-half broadcast */                              \
    float rr; LOBCAST(sig, rr);                                         \
    const float npre = fmaf(rr, preh, prex);                            \
    const float nn = fmaf(-2.0f, frcp(fexp2(npre) + 1.0f), 1.0f);       \
    /* n_i -> h-lane: hi-half broadcast */                              \
    float nh; HIBCAST(nn, nh);                                          \
    const float zz = __uint_as_float((unsigned)zzi);                    \
    h = fmaf(zz, h - nh, nh);                                           \
    _Pragma("unroll")                                                   \
    for (int _j = 0; _j < 9; ++_j) {                                    \
      sh2[_j].x = rl(h, 2 * _j);                                        \
      sh2[_j].y = rl(h, 2 * _j + 1);                                    \
    }                                                                   \
    sh2[9].x = rl(h, 18); sh2[9].y = 0.0f;                              \
    v2f oA = {bo, 0.0f}, oB = {0.0f, 0.0f};                             \
    _Pragma("unroll")                                                   \
    for (int _j = 0; _j < 5; ++_j) oA = vfma(sh2[_j], wo2[_j], oA);     \
    _Pragma("unroll")                                                   \
    for (int _j = 5; _j < 10; ++_j) oB = vfma(sh2[_j], wo2[_j], oB);    \
    const v2f ov = oA + oB;                                             \
    if (lane == 0) out[(size_t)(tcur) * NB + b] = ov.x + ov.y;          \
  } while (0)

  for (int t = 0; t < TT; t += 4) {
    STEP(xA, t);
    { const int tn = (t + 4 < TT) ? t + 4 : TT - 1; LOADROW(xA, tn); }
    STEP(xB, t + 1);
    { const int tn = (t + 5 < TT) ? t + 5 : TT - 1; LOADROW(xB, tn); }
    STEP(xC, t + 2);
    { const int tn = (t + 6 < TT) ? t + 6 : TT - 1; LOADROW(xC, tn); }
    STEP(xD, t + 3);
    { const int tn = (t + 7 < TT) ? t + 7 : TT - 1; LOADROW(xD, tn); }
  }

#undef LOADROW
#undef STEP
#undef LOBCAST
#undef HIBCAST
}

extern "C" void kernel_launch(void* const* d_in, const int* in_sizes, int n_in,
                              void* d_out, int out_size, void* d_ws, size_t ws_size,
                              hipStream_t stream) {
  const float* x    = (const float*)d_in[0];
  const float* Wih  = (const float*)d_in[1];
  const float* Whh  = (const float*)d_in[2];
  const float* bih  = (const float*)d_in[3];
  const float* bhh  = (const float*)d_in[4];
  const float* Wout = (const float*)d_in[5];
  const float* bout = (const float*)d_in[6];
  float* out = (float*)d_out;

  gru57_v2<<<dim3(NB), dim3(64), 0, stream>>>(
      x, Wih, Whh, bih, bhh, Wout, bout, out);
}